// Round 3
// baseline (41455.118 us; speedup 1.0000x reference)
//
#include <hip/hip_runtime.h>

#define TSTEPS 2048
#define VDIM 128
#define FDIM 512

typedef __attribute__((ext_vector_type(8))) _Float16 half8;
typedef __attribute__((ext_vector_type(4))) _Float16 half4;
typedef __attribute__((ext_vector_type(4))) float floatx4;

// ws layout: [0,512K) WH f16 hi, A-frag order [wf32][kk16][lane64][e8]
//            [512K,1024K) WL f16 lo*4096, same order
#define WS_WH 0
#define WS_WL (512u * 1024u)

// Pre-swizzle W (fp32 row-major [j][k]) into A-fragment order, split into
// f16 hi + f16 lo*4096.  A-frag (16x16x32): lane l holds row (l&15),
// k = 8*(l>>4) + e within each K=32 block kk.
__global__ __launch_bounds__(256) void rnn_prep(const float* __restrict__ W,
                                                _Float16* __restrict__ WH,
                                                _Float16* __restrict__ WL) {
  int tid = blockIdx.x * 256 + threadIdx.x;   // 0..32767 (32 wf * 16 kk * 64 l)
  int wf = tid >> 10;
  int kk = (tid >> 6) & 15;
  int l  = tid & 63;
  int j  = 16 * wf + (l & 15);
  int k0 = kk * 32 + (l >> 4) * 8;
  const float* src = W + j * FDIM + k0;
  half8 vh, vl;
#pragma unroll
  for (int e = 0; e < 8; ++e) {
    float w = src[e];
    _Float16 h = (_Float16)w;
    vh[e] = h;
    vl[e] = (_Float16)((w - (float)h) * 4096.0f);
  }
  *(half8*)(WH + (size_t)tid * 8) = vh;
  *(half8*)(WL + (size_t)tid * 8) = vl;
}

// 16 WGs, each fully independent: WG hg owns state rows [8*hg, 8*hg+8) and
// holds ALL of W (hi+lo) in VGPRs across its 16 waves (32 features/wave).
// r for the 8 rows lives in LDS in B-frag order, double-buffered; one
// __syncthreads per step; NO cross-WG communication at all.
// MFMA: D[j][i] = sum_k W[j][k] * r[i][k]; A=W (VGPR), B=r (LDS frags).
// B-frag cols 8..15 read duplicates of cols 0..7 (bank broadcast, free).
__global__ void __launch_bounds__(1024)
rnn_main(const float* __restrict__ X, const float* __restrict__ bvec,
         const _Float16* __restrict__ WH, const _Float16* __restrict__ WL,
         float* __restrict__ out) {
  __shared__ _Float16 rbuf[2][8192];          // [buf][kk16][lane64][e8], 16KB each
  const int hg = blockIdx.x;                  // half-group: rows 8*hg..8*hg+7
  const int w  = threadIdx.x >> 6;            // wave 0..15: features 32w..32w+31
  const int l  = threadIdx.x & 63;
  const int lr = l & 15;                      // D col = local row index
  const int lg = l >> 4;

  // persistent W fragments: 2 tiles x 16 kk x (hi,lo) = 256 VGPRs, pinned
  half8 wh[2][16], wl[2][16];
#pragma unroll
  for (int T = 0; T < 2; ++T)
#pragma unroll
    for (int kk = 0; kk < 16; ++kk) {
      wh[T][kk] = ((const half8*)WH)[((2 * w + T) * 16 + kk) * 64 + l];
      wl[T][kk] = ((const half8*)WL)[((2 * w + T) * 16 + kk) * 64 + l];
      asm volatile("" : "+v"(wh[T][kk]), "+v"(wl[T][kk]));
    }

  const int jb0 = 32 * w + lg * 4;            // tile0 features jb0..jb0+3
  const int jb1 = jb0 + 16;                   // tile1
  const floatx4 bv0 = *(const floatx4*)(bvec + jb0);
  const floatx4 bv1 = *(const floatx4*)(bvec + jb1);
  const bool vis = (w < 4);                   // features < 128

  // frag-order write offsets (halves): off(j0) = (j0>>5)*512 + ((j0>>3)&3)*128
  //                                             + col*8 + (j0&7)   (col = lr<8)
  const int wo0 = ((jb0 >> 5) << 9) + (((jb0 >> 3) & 3) << 7) + (lr << 3) + (jb0 & 7);
  const int wo1 = ((jb1 >> 5) << 9) + (((jb1 >> 3) & 3) << 7) + (lr << 3) + (jb1 & 7);
  // frag read offset (halves): col duplication (l&7) -> bank broadcast
  const int ro = (lg * 16 + (l & 7)) * 8;
  // diagonal bookkeeping: diag feature j == global row i = 8*hg + col
  const int dj = (hg & 1) * 8 + lr;           // j&15 of this lane's diag target
  const bool dT0 = (2 * w == (hg >> 1));
  const bool dT1 = (2 * w + 1 == (hg >> 1));

  // zero r(0)
  { half8 z{}; ((half8*)rbuf[0])[threadIdx.x] = z; }
  __syncthreads();

  for (int t = 0; t < TSTEPS; ++t) {
    floatx4 xv0{0.f,0.f,0.f,0.f}, xv1{0.f,0.f,0.f,0.f};
    if (vis) {
      xv0 = *(const floatx4*)(X + t * VDIM + jb0);
      xv1 = *(const floatx4*)(X + t * VDIM + jb1);
    }
    const _Float16* rb = rbuf[t & 1];
    floatx4 a0{0.f,0.f,0.f,0.f}, a1{0.f,0.f,0.f,0.f};
    floatx4 c0{0.f,0.f,0.f,0.f}, c1{0.f,0.f,0.f,0.f};
#pragma unroll
    for (int kk = 0; kk < 16; ++kk) {
      half8 bh = *(const half8*)(rb + kk * 512 + ro);
      a0 = __builtin_amdgcn_mfma_f32_16x16x32_f16(wh[0][kk], bh, a0, 0, 0, 0);
      c0 = __builtin_amdgcn_mfma_f32_16x16x32_f16(wl[0][kk], bh, c0, 0, 0, 0);
      a1 = __builtin_amdgcn_mfma_f32_16x16x32_f16(wh[1][kk], bh, a1, 0, 0, 0);
      c1 = __builtin_amdgcn_mfma_f32_16x16x32_f16(wl[1][kk], bh, c1, 0, 0, 0);
    }

    const bool last = (t == TSTEPS - 1);
    half4 s0, s1;
#pragma unroll
    for (int v = 0; v < 4; ++v) {
      float u0 = a0[v] + c0[v] * 2.44140625e-4f + bv0[v];
      float u1 = a1[v] + c1[v] * 2.44140625e-4f + bv1[v];
      const bool d0 = dT0 && (lg * 4 + v == dj);
      const bool d1 = dT1 && (lg * 4 + v == dj);
      if (vis) {
        if (!d0) u0 = 0.5f * u0 + 0.5f * xv0[v];
        if (!d1) u1 = 0.5f * u1 + 0.5f * xv1[v];
      }
      if (last) {
        if (lr < 8) {
          if (d0) out[8 * hg + lr] = u0;      // pre-tanh diag, Lambda=1 path
          if (d1) out[8 * hg + lr] = u1;
        }
      } else {
        float au0 = fabsf(u0), au1 = fabsf(u1);
        float e0 = __expf(-2.0f * au0), e1 = __expf(-2.0f * au1);
        float t0 = __fdividef(1.0f - e0, 1.0f + e0);
        float t1 = __fdividef(1.0f - e1, 1.0f + e1);
        s0[v] = (_Float16)copysignf(t0, u0);
        s1[v] = (_Float16)copysignf(t1, u1);
      }
    }

    if (!last && lr < 8) {
      _Float16* wb = rbuf[(t + 1) & 1];
      *(half4*)(wb + wo0) = s0;
      *(half4*)(wb + wo1) = s1;
    }
    __syncthreads();
  }
}

extern "C" void kernel_launch(void* const* d_in, const int* in_sizes, int n_in,
                              void* d_out, int out_size, void* d_ws, size_t ws_size,
                              hipStream_t stream) {
  const float* X = (const float*)d_in[0];
  const float* W = (const float*)d_in[1];
  const float* b = (const float*)d_in[2];
  float* out = (float*)d_out;
  char* ws = (char*)d_ws;

  _Float16* WH = (_Float16*)(ws + WS_WH);
  _Float16* WL = (_Float16*)(ws + WS_WL);

  rnn_prep<<<128, 256, 0, stream>>>(W, WH, WL);
  rnn_main<<<16, 1024, 0, stream>>>(X, b, WH, WL, out);
}

// Round 4
// 3926.307 us; speedup vs baseline: 10.5583x; 10.5583x over previous
//
#include <hip/hip_runtime.h>

#define TSTEPS 2048
#define VDIM 128
#define FDIM 512

typedef __attribute__((ext_vector_type(8))) _Float16 half8;
typedef __attribute__((ext_vector_type(4))) _Float16 half4;
typedef __attribute__((ext_vector_type(4))) float floatx4;
typedef unsigned long long u64;

// ws layout (bytes):
//   [0,512K)        WH: f16 hi, frag order [chunk32][kk16][lane64][e8]
//   [512K,1M)       WL: f16 lo*4096, same order
//   [1M,1M+128K)    r parity-0: [g8][kk16][lane64][e8] f16 (16KB/group)
//   [1M+128K,+256K) r parity-1: same
#define WS_WH 0
#define WS_WL (512u * 1024u)
#define WS_R  (1024u * 1024u)

// Pre-swizzle W (fp32 row-major [j][k]) into A-frag order, hi + lo*4096.
// A-frag (16x16x32 f16): lane l holds row (l&15), k = kk*32 + (l>>4)*8 + e.
__global__ __launch_bounds__(256) void rnn_prep(const float* __restrict__ W,
                                                _Float16* __restrict__ WH,
                                                _Float16* __restrict__ WL) {
  int tid = blockIdx.x * 256 + threadIdx.x;   // 32 chunks * 16 kk * 64 lanes
  int c  = tid >> 10;
  int kk = (tid >> 6) & 15;
  int l  = tid & 63;
  int j  = 16 * c + (l & 15);
  int k0 = kk * 32 + (l >> 4) * 8;
  const float* src = W + j * FDIM + k0;
  half8 vh, vl;
#pragma unroll
  for (int e = 0; e < 8; ++e) {
    float w = src[e];
    _Float16 h = (_Float16)w;
    vh[e] = h;
    vl[e] = (_Float16)((w - (float)h) * 4096.0f);
  }
  *(half8*)(WH + (size_t)tid * 8) = vh;
  *(half8*)(WL + (size_t)tid * 8) = vl;
}

// 32 WGs = 8 row-groups (g) x 4 slices (s), 512 thr = 8 waves.
// Wave w of slice s owns feature chunk c = 4w+s (feats 16c..16c+15), W hi+lo
// pinned in 128 VGPRs.  Exchange protocol: r stored in B-frag order in global
// with step-tag tau(t) = (t>>1)&1 embedded in every f16 mantissa LSB.
// Consumers poll the data itself (coherent sc0sc1 loads) until all tags
// match; producers just store.  No atomics, no fences, no counters.
__global__ void __launch_bounds__(512, 2)
rnn_main(const float* __restrict__ X, const float* __restrict__ bvec,
         const _Float16* __restrict__ WH, const _Float16* __restrict__ WL,
         _Float16* __restrict__ rbase, float* __restrict__ out) {
  __shared__ _Float16 lds[2][8192];           // 16KB per step-parity
  const int g  = blockIdx.x & 7;
  const int s  = blockIdx.x >> 3;
  const int w  = threadIdx.x >> 6;
  const int l  = threadIdx.x & 63;
  const int lr = l & 15;                      // D col = group-local state row
  const int lg = l >> 4;
  const int c  = 4 * w + s;                   // W chunk = feats [16c,16c+16)
  const int jb = 16 * c + lg * 4;             // this lane's 4 features

  // persistent W fragments (hi + lo): 128 VGPRs, pinned
  half8 wh[16], wl[16];
#pragma unroll
  for (int kk = 0; kk < 16; ++kk) {
    wh[kk] = ((const half8*)WH)[(c * 16 + kk) * 64 + l];
    wl[kk] = ((const half8*)WL)[(c * 16 + kk) * 64 + l];
    asm volatile("" : "+v"(wh[kk]), "+v"(wl[kk]));
  }

  const floatx4 bv = *(const floatx4*)(bvec + jb);
  const bool vis = (16 * c < 128);
  const bool diagHere = (c == g);             // chunk holding group g's diag
  const u64 TAGM = 0x0001000100010001ULL;

  // poll chunks: this wave owns kk = 2w, 2w+1; byte offset kk*1024 + l*16
  const int pc = (2 * w) * 1024 + l * 16;
  // produced half4 frag offset (halves): kk*512 + (sub*16+lr)*8 + (jb&7)
  const int so = ((jb >> 5) << 9) + ((((jb >> 3) & 3) << 4) + lr) * 8 + (jb & 7);

  int budget = 4000000;                       // global anti-hang budget

  for (int t = 0; t < TSTEPS; ++t) {
    floatx4 xv = {0.f, 0.f, 0.f, 0.f};
    if (vis) xv = *(const floatx4*)(X + t * VDIM + jb);

    // ---- poll r(t): buf parity t&1, expect tag (t>>1)&1 on every f16 LSB
    const char* rb = (const char*)rbase + (size_t)(t & 1) * (128 * 1024)
                   + (size_t)g * 16384;
    const u64 want = (u64)((t >> 1) & 1) * TAGM;
    u64 v0, v1, v2, v3;
    for (;;) {
      v0 = __hip_atomic_load((const u64*)(rb + pc),        __ATOMIC_RELAXED,
                             __HIP_MEMORY_SCOPE_AGENT);
      v1 = __hip_atomic_load((const u64*)(rb + pc + 8),    __ATOMIC_RELAXED,
                             __HIP_MEMORY_SCOPE_AGENT);
      v2 = __hip_atomic_load((const u64*)(rb + pc + 1024), __ATOMIC_RELAXED,
                             __HIP_MEMORY_SCOPE_AGENT);
      v3 = __hip_atomic_load((const u64*)(rb + pc + 1032), __ATOMIC_RELAXED,
                             __HIP_MEMORY_SCOPE_AGENT);
      int ok = ((v0 & TAGM) == want) & ((v1 & TAGM) == want) &
               ((v2 & TAGM) == want) & ((v3 & TAGM) == want);
      if (__all(ok)) break;
      if (--budget < 0) break;
    }

    // ---- stash this wave's 2 chunks into LDS (linear frag order)
    char* lp = (char*)lds[t & 1];
    { ulonglong2 a; a.x = v0; a.y = v1; *(ulonglong2*)(lp + pc) = a; }
    { ulonglong2 a; a.x = v2; a.y = v3; *(ulonglong2*)(lp + pc + 1024) = a; }
    __syncthreads();

    // ---- MFMA: D[j][i] = sum_k W[j,k] r[i,k], 16 kk x (hi,lo)
    floatx4 aH = {0.f,0.f,0.f,0.f}, aL = {0.f,0.f,0.f,0.f};
#pragma unroll
    for (int kk = 0; kk < 16; ++kk) {
      half8 bh = *(const half8*)(lp + kk * 1024 + l * 16);
      aH = __builtin_amdgcn_mfma_f32_16x16x32_f16(wh[kk], bh, aH, 0, 0, 0);
      aL = __builtin_amdgcn_mfma_f32_16x16x32_f16(wl[kk], bh, aL, 0, 0, 0);
    }

    // ---- epilogue: combine, blend, tanh, tag, store r(t+1)
    const bool last = (t == TSTEPS - 1);
    union { half4 h; u64 u; } pk;
#pragma unroll
    for (int v = 0; v < 4; ++v) {
      float u = aH[v] + aL[v] * 2.44140625e-4f + bv[v];
      const bool isdiag = diagHere && (lg * 4 + v == lr);
      if (vis && !isdiag) u = 0.5f * u + 0.5f * xv[v];
      if (last) {
        if (isdiag) out[16 * g + lr] = u;     // diag of U, pre-tanh
      } else {
        float au = fabsf(u);
        float e2 = __expf(-2.0f * au);
        float th = __fdividef(1.0f - e2, 1.0f + e2);
        pk.h[v] = (_Float16)copysignf(th, u);
      }
    }

    if (!last) {
      const u64 ntag = (u64)(((t + 1) >> 1) & 1) * TAGM;
      u64 val = (pk.u & ~TAGM) | ntag;
      char* wbuf = (char*)rbase + (size_t)((t + 1) & 1) * (128 * 1024)
                 + (size_t)g * 16384;
      __hip_atomic_store((u64*)(wbuf + so * 2), val, __ATOMIC_RELAXED,
                         __HIP_MEMORY_SCOPE_AGENT);
    }
  }
}

extern "C" void kernel_launch(void* const* d_in, const int* in_sizes, int n_in,
                              void* d_out, int out_size, void* d_ws, size_t ws_size,
                              hipStream_t stream) {
  const float* X = (const float*)d_in[0];
  const float* W = (const float*)d_in[1];
  const float* b = (const float*)d_in[2];
  float* out = (float*)d_out;
  char* ws = (char*)d_ws;

  _Float16* WH = (_Float16*)(ws + WS_WH);
  _Float16* WL = (_Float16*)(ws + WS_WL);
  _Float16* rb = (_Float16*)(ws + WS_R);

  // parity-0 r: zeros (valid r(0), tag 0).  parity-1: 0x0101 (LSB=1, invalid
  // for tau(1)=0, so step-1 consumers cannot accept stale bytes).
  hipMemsetAsync(ws + WS_R, 0x00, 128 * 1024, stream);
  hipMemsetAsync(ws + WS_R + 128 * 1024, 0x01, 128 * 1024, stream);
  rnn_prep<<<128, 256, 0, stream>>>(W, WH, WL);
  rnn_main<<<32, 512, 0, stream>>>(X, b, WH, WL, rb, out);
}